// Round 1
// baseline (119.263 us; speedup 1.0000x reference)
//
#include <hip/hip_runtime.h>
#include <math.h>

// Problem shape (fixed by the reference): B=4, S=4, N=2048, D=2048
#define NB 4
#define NS 4
#define NT 5      // S+1
#define NN 2048
#define ND 2048
#define NTHREADS 256
// 28 block-wide reductions: p[s*7+0] = ssq[s]; p[s*7+1+j] = dot(x[s], (1+g)*w_j), j=0..5
#define NRED 28

__global__ __launch_bounds__(NTHREADS, 4)
void hyperconn_kernel(const float* __restrict__ residuals,
                      const float* __restrict__ gamma,
                      const float* __restrict__ w_alpha,
                      const float* __restrict__ scale_alpha,
                      const float* __restrict__ static_alpha,
                      const float* __restrict__ w_beta,
                      const float* __restrict__ scale_beta,
                      const float* __restrict__ static_beta,
                      float* __restrict__ out)
{
    const int tid = threadIdx.x;
    const int bn  = blockIdx.x;          // 0 .. NB*NN-1
    const int b   = bn >> 11;            // bn / NN
    const int n   = bn & (NN - 1);       // bn % NN

    // Two contiguous float4 chunks per thread: d0 in [0,1024), d1 in [1024,2048)
    const int d0 = tid << 2;
    const int d1 = d0 + (ND >> 1);

    const size_t row_stride = (size_t)NN * ND;
    const float* xbase = residuals + (size_t)(b * NS) * row_stride + (size_t)n * ND;

    // ---- Load the 4 input rows' slices into registers (the only HBM read) ----
    float xa[NS][8];
#pragma unroll
    for (int s = 0; s < NS; ++s) {
        const float* r = xbase + (size_t)s * row_stride;
        *reinterpret_cast<float4*>(&xa[s][0]) = *reinterpret_cast<const float4*>(r + d0);
        *reinterpret_cast<float4*>(&xa[s][4]) = *reinterpret_cast<const float4*>(r + d1);
    }

    // ---- Partial sums: 4 ssq + 4x6 dots (weights are L1/L2-resident, tiny) ----
    float p[NRED];
#pragma unroll
    for (int k = 0; k < NRED; ++k) p[k] = 0.f;

#pragma unroll
    for (int c = 0; c < 2; ++c) {
        const int d = (c == 0) ? d0 : d1;
        float g[4];
        *reinterpret_cast<float4*>(&g[0]) = *reinterpret_cast<const float4*>(gamma + d);
#pragma unroll
        for (int e = 0; e < 4; ++e) g[e] += 1.f;

#pragma unroll
        for (int s = 0; s < NS; ++s) {
#pragma unroll
            for (int e = 0; e < 4; ++e) {
                const float xv = xa[s][c * 4 + e];
                p[s * 7 + 0] += xv * xv;
            }
        }

#pragma unroll
        for (int j = 0; j < 6; ++j) {
            const float* wsrc = (j < 5) ? (w_alpha + (size_t)j * ND + d) : (w_beta + d);
            float w[4];
            *reinterpret_cast<float4*>(&w[0]) = *reinterpret_cast<const float4*>(wsrc);
#pragma unroll
            for (int e = 0; e < 4; ++e) w[e] *= g[e];
#pragma unroll
            for (int s = 0; s < NS; ++s) {
#pragma unroll
                for (int e = 0; e < 4; ++e) {
                    p[s * 7 + 1 + j] += xa[s][c * 4 + e] * w[e];
                }
            }
        }
    }

    // ---- Wave-level butterfly reduce (all 64 lanes end with the wave sum) ----
#pragma unroll
    for (int k = 0; k < NRED; ++k) {
        float v = p[k];
        v += __shfl_xor(v, 1);
        v += __shfl_xor(v, 2);
        v += __shfl_xor(v, 4);
        v += __shfl_xor(v, 8);
        v += __shfl_xor(v, 16);
        v += __shfl_xor(v, 32);
        p[k] = v;
    }

    __shared__ float red[4][NRED];       // per-wave sums
    __shared__ float asb[NS][6];         // [s][0..4]=alpha, [s][5]=beta
    __shared__ float Msh[16];            // final 4x4 mixing matrix

    const int wave = tid >> 6;
    const int lane = tid & 63;
    if (lane == 0) {
#pragma unroll
        for (int k = 0; k < NRED; ++k) red[wave][k] = p[k];
    }
    __syncthreads();

    // ---- 24 threads in parallel: one tanh each ----
    if (tid < 24) {
        const int s = tid / 6;
        const int j = tid % 6;
        const float ssq = red[0][s * 7] + red[1][s * 7] + red[2][s * 7] + red[3][s * 7];
        const float dot = red[0][s * 7 + 1 + j] + red[1][s * 7 + 1 + j]
                        + red[2][s * 7 + 1 + j] + red[3][s * 7 + 1 + j];
        const float rs  = sqrtf((float)ND) / fmaxf(sqrtf(ssq), 1e-12f);
        const float th  = tanhf(dot * rs);
        asb[s][j] = (j < 5) ? (th * scale_alpha[0] + static_alpha[s * 5 + j])
                            : (th * scale_beta[0]  + static_beta[s]);
    }
    __syncthreads();

    // ---- M[so][si] = beta[so]*alpha[si][0] + alpha[si][so+1] ----
    if (tid < 16) {
        const int so = tid >> 2;
        const int si = tid & 3;
        Msh[tid] = asb[so][5] * asb[si][0] + asb[si][so + 1];
    }
    __syncthreads();

    float M[16];
#pragma unroll
    for (int k = 0; k < 16; ++k) M[k] = Msh[k];

    // ---- out[so][d] = sum_si M[so][si] * x[si][d]  (the only HBM write) ----
    float* obase = out + (size_t)(b * NS) * row_stride + (size_t)n * ND;
#pragma unroll
    for (int so = 0; so < NS; ++so) {
        float o[8];
#pragma unroll
        for (int e = 0; e < 8; ++e) {
            o[e] = M[so * 4 + 0] * xa[0][e]
                 + M[so * 4 + 1] * xa[1][e]
                 + M[so * 4 + 2] * xa[2][e]
                 + M[so * 4 + 3] * xa[3][e];
        }
        float* w = obase + (size_t)so * row_stride;
        *reinterpret_cast<float4*>(w + d0) = *reinterpret_cast<const float4*>(&o[0]);
        *reinterpret_cast<float4*>(w + d1) = *reinterpret_cast<const float4*>(&o[4]);
    }
}

extern "C" void kernel_launch(void* const* d_in, const int* in_sizes, int n_in,
                              void* d_out, int out_size, void* d_ws, size_t ws_size,
                              hipStream_t stream) {
    const float* residuals    = (const float*)d_in[0];
    const float* gamma        = (const float*)d_in[1];
    const float* w_alpha      = (const float*)d_in[2];
    const float* scale_alpha  = (const float*)d_in[3];
    const float* static_alpha = (const float*)d_in[4];
    const float* w_beta       = (const float*)d_in[5];
    const float* scale_beta   = (const float*)d_in[6];
    const float* static_beta  = (const float*)d_in[7];
    float* out = (float*)d_out;

    const int grid = NB * NN;  // 8192 blocks, one per (b, n)
    hyperconn_kernel<<<grid, NTHREADS, 0, stream>>>(
        residuals, gamma, w_alpha, scale_alpha, static_alpha,
        w_beta, scale_beta, static_beta, out);
}